// Round 6
// baseline (209039.551 us; speedup 1.0000x reference)
//
#include <hip/hip_runtime.h>

#define HH    100
#define LSEQ  168
#define STEPS 48
#define NTICK 8066     // L0 at tick t (t<8064), L1 at tick t-1
#define SHP   112      // padded h stride (zeros beyond 100)
#define NSTR  368      // streamed full rows = Whh1 rows 32..399 (units 832..1199)
#define NLROW 320      // LDS-resident full rows (units 512..831)

// LDS float offsets (dynamic shared, 139,408 B)
#define OFF_W  0                 // [25][NLROW] float4 = 32,000 fl (transposed: lane-stride 16B)
#define OFF_H  32000             // h: [L0b0][L0b1][L1b0][L1b1] x SHP = 448 fl, zero-padded
#define OFF_G  32448             // G[1200] float2 (batchA,batchB) = 2400 fl
#define OFF_Y  34848             // yacc[2], ybuf[2]
#define NLDS   34852
#define LDS_BYTES (NLDS * 4)

#define H0A (OFF_H)
#define H0B (OFF_H + SHP)
#define H1A (OFF_H + 2 * SHP)
#define H1B (OFF_H + 3 * SHP)

#define WS_BYTES (25 * NSTR * 4 * 4)   // 147,200 B packed stream weights

__device__ __forceinline__ float sigmoidf_(float x) {
    return 1.0f / (1.0f + __expf(-x));
}
__device__ __forceinline__ float tanhf_(float x) {
    return 1.0f - 2.0f / (__expf(2.0f * x) + 1.0f);
}

#define DOT4(acc, w4, h4) acc += (w4).x*(h4).x + (w4).y*(h4).y + (w4).z*(h4).z + (w4).w*(h4).w
#define RED4(x) { x += __shfl_xor(x, 1); x += __shfl_xor(x, 2); }

// Pack streamed Whh1 rows 32..399 as wsT4[kc][r] (r contiguous -> coalesced dwordx4).
__global__ void prep_kernel(const float* __restrict__ Whh1, float* __restrict__ wsT) {
    int idx = blockIdx.x * 256 + threadIdx.x;       // f4 index
    if (idx >= 25 * NSTR) return;
    int kc = idx / NSTR, r = idx % NSTR;
    const float* src = Whh1 + (32 + r) * HH + 4 * kc;
    float4 w4 = *(const float4*)src;                // rows are 400 B = 16B-aligned
    *(float4*)&wsT[idx * 4] = w4;
}

// Unit map (1200 units, unit u = one gate-row dot-product; G[u] holds (bA,bB)):
//   u <  400 : Whh0 row u      (input h0) -> L0 gates
//   u <  800 : Wih1 row u-400  (input h0) -> L1 "a"
//   u < 1200 : Whh1 row u-800  (input h1) -> L1 "b"
// Storage: u<512 regs (thread v=t>>2 owns k-window s=t&3 of rows {2v,2v+1} arch +
// {256+2v,257+2v} AGPR; shfl-reduced over s). u in [512,832) LDS full rows
// (1/lane, t<320). u in [832,1200) streamed full rows (rowA: t>=320; rowB: t in [64,240)).
template <bool PACKED>
__global__
__attribute__((amdgpu_flat_work_group_size(512, 512), amdgpu_waves_per_eu(2, 2)))
void lstm_kernel(const float* __restrict__ X,     // (512,168)
                 const float* __restrict__ Wih0,  // (400,1)
                 const float* __restrict__ Whh0,  // (400,100)
                 const float* __restrict__ bih0,
                 const float* __restrict__ bhh0,
                 const float* __restrict__ Wih1,  // (400,100)
                 const float* __restrict__ Whh1,  // (400,100)
                 const float* __restrict__ bih1,
                 const float* __restrict__ bhh1,
                 const float* __restrict__ fcw,   // (100)
                 const float* __restrict__ fcb,   // (1)
                 const float* __restrict__ wsT,   // packed stream weights (or unused)
                 float* __restrict__ out)         // (512,48)
{
    extern __shared__ float lds[];

    const int t  = threadIdx.x;
    const int s  = t & 3;
    const int v  = t >> 2;
    const int kb = s * 28;
    const int b0 = blockIdx.x * 2;

    // ---- one-time init ----
    for (int i = t; i < 4 * SHP; i += 512) lds[OFF_H + i] = 0.0f;
    if (t < 4) lds[OFF_Y + t] = 0.0f;
    for (int c = t; c < 25 * NLROW; c += 512) {     // transposed LDS weight fill
        int kc = c / NLROW, i = c % NLROW;
        const float* src = (i < 288) ? (Wih1 + (112 + i) * HH + 4 * kc)
                                     : (Whh1 + (i - 288) * HH + 4 * kc);
        *(float4*)&lds[OFF_W + c * 4] = *(const float4*)src;
    }
    const float fcb0 = fcb[0];

    // ---- arch reg slices: window s of Whh0 rows 2v, 2v+1 ----
    float4 aw0[7], aw1[7];
    {
        const float* r0 = Whh0 + (2 * v) * HH;
        const float* r1 = Whh0 + (2 * v + 1) * HH;
        #pragma unroll
        for (int i = 0; i < 7; ++i) {
            const int k0 = kb + 4 * i;
            if (k0 < HH) { aw0[i] = *(const float4*)(r0 + k0);
                           aw1[i] = *(const float4*)(r1 + k0); }
            else { aw0[i] = make_float4(0.f,0.f,0.f,0.f);
                   aw1[i] = make_float4(0.f,0.f,0.f,0.f); }
        }
    }
    // ---- AGPR reg slices: window s of rows 256+2v, 257+2v ----
    float4 qw0[7], qw1[7];
    {
        const int u0 = 256 + 2 * v, u1 = u0 + 1;
        const float* r0 = (u0 < 400) ? (Whh0 + u0 * HH) : (Wih1 + (u0 - 400) * HH);
        const float* r1 = (u1 < 400) ? (Whh0 + u1 * HH) : (Wih1 + (u1 - 400) * HH);
        #pragma unroll
        for (int i = 0; i < 7; ++i) {
            const int k0 = kb + 4 * i;
            if (k0 < HH) { qw0[i] = *(const float4*)(r0 + k0);
                           qw1[i] = *(const float4*)(r1 + k0); }
            else { qw0[i] = make_float4(0.f,0.f,0.f,0.f);
                   qw1[i] = make_float4(0.f,0.f,0.f,0.f); }
        }
    }
    // One-time AGPR placement (outside the loop — R4's in-loop pins forced
    // per-tick traffic; demand 56 <= 128 AGPRs so no spill path exists).
    #pragma unroll
    for (int i = 0; i < 7; ++i) {
        asm volatile("" : "+a"(qw0[i].x), "+a"(qw0[i].y), "+a"(qw0[i].z), "+a"(qw0[i].w),
                          "+a"(qw1[i].x), "+a"(qw1[i].y), "+a"(qw1[i].z), "+a"(qw1[i].w));
    }

    // ---- Phase-B constants in registers ----
    int ub = 0, uj = 0;
    float pbb[4] = {0.f,0.f,0.f,0.f}, pwx[4] = {0.f,0.f,0.f,0.f}, fcwr = 0.f;
    if (t < 200) {
        ub = t / 100; uj = t % 100;
        #pragma unroll
        for (int g = 0; g < 4; ++g) {
            pbb[g] = bih0[g * 100 + uj] + bhh0[g * 100 + uj];
            pwx[g] = Wih0[g * 100 + uj];
        }
        fcwr = fcw[uj];
    } else if (t < 400) {
        ub = (t - 200) / 100; uj = (t - 200) % 100;
        #pragma unroll
        for (int g = 0; g < 4; ++g)
            pbb[g] = bih1[g * 100 + uj] + bhh1[g * 100 + uj];
    }
    const float* xrow = X + (b0 + ub) * LSEQ;

    // ---- stream task setup ----
    const bool hasA = (t >= 320);
    const bool hasB = (t >= 64 && t < 240);
    const int rA = t - 320;          // stream rows 0..191
    const int rB = t + 128;          // stream rows 192..367
    const float* wspA = PACKED ? (wsT + rA * 4) : (Whh1 + (32 + rA) * HH);
    const float* wspB = PACKED ? (wsT + rB * 4) : (Whh1 + (32 + rB) * HH);
    const int lhoff = (t < 288) ? H0A : H1A;   // LDS full-row input base

    float c0 = 0.0f, c1 = 0.0f;

    __syncthreads();

    #pragma unroll 1
    for (int tick = 0; tick < NTICK; ++tick) {
        const bool ydtick = (tick >= 2) && ((tick - 2) % LSEQ == (LSEQ - 1));

        // ======== Phase A ========
        // (1) reg slices, input h0, both batches; shfl-reduce over s.
        {
            float r0A=0.f,r0B=0.f,r1A=0.f,r1B=0.f,q0A=0.f,q0B=0.f,q1A=0.f,q1B=0.f;
            #pragma unroll
            for (int i = 0; i < 7; ++i) {
                const float4 hA = *(const float4*)&lds[H0A + kb + 4 * i];
                const float4 hB = *(const float4*)&lds[H0B + kb + 4 * i];
                DOT4(r0A, aw0[i], hA); DOT4(r0B, aw0[i], hB);
                DOT4(r1A, aw1[i], hA); DOT4(r1B, aw1[i], hB);
                DOT4(q0A, qw0[i], hA); DOT4(q0B, qw0[i], hB);
                DOT4(q1A, qw1[i], hA); DOT4(q1B, qw1[i], hB);
            }
            RED4(r0A); RED4(r0B); RED4(r1A); RED4(r1B);
            RED4(q0A); RED4(q0B); RED4(q1A); RED4(q1B);
            if (s == 0) {
                *(float2*)&lds[OFF_G + (2 * v) * 2]     = make_float2(r0A, r0B);
                *(float2*)&lds[OFF_G + (2 * v + 1) * 2] = make_float2(r1A, r1B);
            } else if (s == 1) {
                *(float2*)&lds[OFF_G + (256 + 2 * v) * 2] = make_float2(q0A, q0B);
                *(float2*)&lds[OFF_G + (257 + 2 * v) * 2] = make_float2(q1A, q1B);
            }
        }
        // (2) LDS full row: unit 512+t (t<320), transposed reads (lane-stride 16B).
        if (t < NLROW) {
            float aA = 0.f, aB = 0.f;
            #pragma unroll
            for (int kc = 0; kc < 25; ++kc) {
                const float4 w4 = *(const float4*)&lds[OFF_W + (kc * NLROW + t) * 4];
                const float4 hA = *(const float4*)&lds[lhoff + 4 * kc];
                const float4 hB = *(const float4*)&lds[lhoff + SHP + 4 * kc];
                DOT4(aA, w4, hA); DOT4(aB, w4, hB);
            }
            *(float2*)&lds[OFF_G + (512 + t) * 2] = make_float2(aA, aB);
        }
        // (3) streamed full rows: units 832+r, input h1, coalesced dwordx4.
        if (hasA) {
            float aA = 0.f, aB = 0.f;
            #pragma unroll
            for (int kc = 0; kc < 25; ++kc) {
                const float4 w4 = PACKED ? *(const float4*)(wspA + kc * (NSTR * 4))
                                         : *(const float4*)(wspA + 4 * kc);
                const float4 hA = *(const float4*)&lds[H1A + 4 * kc];
                const float4 hB = *(const float4*)&lds[H1B + 4 * kc];
                DOT4(aA, w4, hA); DOT4(aB, w4, hB);
            }
            *(float2*)&lds[OFF_G + (832 + rA) * 2] = make_float2(aA, aB);
        }
        if (hasB) {
            float aA = 0.f, aB = 0.f;
            #pragma unroll
            for (int kc = 0; kc < 25; ++kc) {
                const float4 w4 = PACKED ? *(const float4*)(wspB + kc * (NSTR * 4))
                                         : *(const float4*)(wspB + 4 * kc);
                const float4 hA = *(const float4*)&lds[H1A + 4 * kc];
                const float4 hB = *(const float4*)&lds[H1B + 4 * kc];
                DOT4(aA, w4, hA); DOT4(aB, w4, hB);
            }
            *(float2*)&lds[OFF_G + (832 + rB) * 2] = make_float2(aA, aB);
        }
        // (4) fc dot (rare), reads stable h1
        if (ydtick && t < 200) {
            atomicAdd(&lds[OFF_Y + ub], fcwr * lds[H1A + ub * SHP + uj]);
        }
        __syncthreads();

        // ======== Phase B ========
        if (t < 200) {
            if (tick < 8064) {               // L0, global step = tick
                const int st = tick / LSEQ, p = tick % LSEQ;
                float x;
                if (st == 0)           x = xrow[p];
                else if (p < LSEQ - 1) x = xrow[p + 1];
                else                   x = lds[OFF_Y + 2 + ub];
                float Gt[4];
                #pragma unroll
                for (int g = 0; g < 4; ++g)
                    Gt[g] = pbb[g] + pwx[g] * x + lds[OFF_G + (g * 100 + uj) * 2 + ub];
                c0 = sigmoidf_(Gt[1]) * c0 + sigmoidf_(Gt[0]) * tanhf_(Gt[2]);
                lds[OFF_H + ub * SHP + uj] = sigmoidf_(Gt[3]) * tanhf_(c0);
            }
        } else if (t < 400) {
            if (tick >= 1 && tick <= 8064) { // L1, global step = tick-1
                float Gt[4];
                #pragma unroll
                for (int g = 0; g < 4; ++g)
                    Gt[g] = pbb[g] + lds[OFF_G + (400 + g * 100 + uj) * 2 + ub]
                                   + lds[OFF_G + (800 + g * 100 + uj) * 2 + ub];
                c1 = sigmoidf_(Gt[1]) * c1 + sigmoidf_(Gt[0]) * tanhf_(Gt[2]);
                lds[H1A + ub * SHP + uj] = sigmoidf_(Gt[3]) * tanhf_(c1);
            }
        } else if (t == 511) {
            if (ydtick) {
                const int st = (tick - 2) / LSEQ;
                const float y0 = lds[OFF_Y + 0] + fcb0;
                const float y1 = lds[OFF_Y + 1] + fcb0;
                lds[OFF_Y + 2] = y0; lds[OFF_Y + 3] = y1;
                out[b0 * STEPS + st]       = y0;
                out[(b0 + 1) * STEPS + st] = y1;
                lds[OFF_Y + 0] = 0.0f; lds[OFF_Y + 1] = 0.0f;
            }
        }
        __syncthreads();
    }
}

extern "C" void kernel_launch(void* const* d_in, const int* in_sizes, int n_in,
                              void* d_out, int out_size, void* d_ws, size_t ws_size,
                              hipStream_t stream) {
    const float* X    = (const float*)d_in[0];
    const float* Wih0 = (const float*)d_in[1];
    const float* Whh0 = (const float*)d_in[2];
    const float* bih0 = (const float*)d_in[3];
    const float* bhh0 = (const float*)d_in[4];
    const float* Wih1 = (const float*)d_in[5];
    const float* Whh1 = (const float*)d_in[6];
    const float* bih1 = (const float*)d_in[7];
    const float* bhh1 = (const float*)d_in[8];
    const float* fcw  = (const float*)d_in[9];
    const float* fcb  = (const float*)d_in[10];
    float* out = (float*)d_out;
    float* wsT = (float*)d_ws;

    static_assert(LDS_BYTES <= 163840, "LDS over 160 KiB");
    if (ws_size >= (size_t)WS_BYTES) {
        (void)hipFuncSetAttribute((const void*)lstm_kernel<true>,
                                  hipFuncAttributeMaxDynamicSharedMemorySize, LDS_BYTES);
        hipLaunchKernelGGL(prep_kernel, dim3((25 * NSTR + 255) / 256), dim3(256), 0, stream,
                           Whh1, wsT);
        hipLaunchKernelGGL(lstm_kernel<true>, dim3(256), dim3(512), LDS_BYTES, stream,
                           X, Wih0, Whh0, bih0, bhh0, Wih1, Whh1, bih1, bhh1,
                           fcw, fcb, wsT, out);
    } else {
        (void)hipFuncSetAttribute((const void*)lstm_kernel<false>,
                                  hipFuncAttributeMaxDynamicSharedMemorySize, LDS_BYTES);
        hipLaunchKernelGGL(lstm_kernel<false>, dim3(256), dim3(512), LDS_BYTES, stream,
                           X, Wih0, Whh0, bih0, bhh0, Wih1, Whh1, bih1, bhh1,
                           fcw, fcb, wsT, out);
    }
}